// Round 20
// baseline (170.292 us; speedup 1.0000x reference)
//
#include <hip/hip_runtime.h>

#define EPSF 1e-5f
#define NSEG 2048
#define NTHR 1024    // 16 waves
#define NWAVE 16
#define NBLK 256

typedef short s16x8 __attribute__((ext_vector_type(8)));
typedef float f32x16 __attribute__((ext_vector_type(16)));
typedef unsigned u32;

__device__ __forceinline__ u32 f2bfu(float f) {
  u32 u = __float_as_uint(f);
  u += 0x7FFFu + ((u >> 16) & 1u);  // RNE; no NaN/Inf in data
  return u >> 16;
}
__device__ __forceinline__ u32 pk2(float a, float b) {  // prep path only
  return f2bfu(a) | (f2bfu(b) << 16);
}
// v_cvt_pk_bf16_f32: dst = {lo=bf16(a), hi=bf16(b)} — 1 VALU op
__device__ __forceinline__ u32 cvtpk(float a, float b) {
  u32 r;
  asm("v_cvt_pk_bf16_f32 %0, %1, %2" : "=v"(r) : "v"(a), "v"(b));
  return r;
}

union FragU { s16x8 v; u32 u[4]; };

struct LayerP { const float *W, *b, *g, *be, *m, *v; };

// Fused setup: blocks 0..2 fold BN into weights (bf16; layers 1,2 K-PERMUTED by
// chi(s,hi,j) = 32*(s>>1)+16*(s&1)+4*hi+(j<4 ? j : j+4)); blocks 3+ zero the
// 2.1MB seg accumulator region.
__global__ void setup_kernel(LayerP p0, LayerP p1, LayerP p2,
                             unsigned short* __restrict__ wsW,
                             float* __restrict__ biasf,
                             uint4* __restrict__ zp, int n16) {
  const int b = blockIdx.x;
  const int t = threadIdx.x;
  if (b >= 3) {
    int i = (b - 3) * 256 + t;
    if (i < n16) zp[i] = make_uint4(0u, 0u, 0u, 0u);
    return;
  }
  const int L = b;
  LayerP p = (L == 0) ? p0 : ((L == 1) ? p1 : p2);
  uint2* wdst = (uint2*)(wsW + L * 16384);
  for (int i = 0; i < 8; ++i) {
    int cid = t + i * 256;             // 2048 chunks = 128 rows x 16 chunks(16B)
    int row = cid >> 4, ch = cid & 15;
    float s = p.g[row] * rsqrtf(p.v[row] + EPSF);
    float w[8];
    if (L == 0) {                      // natural order: chunk ch = k 8ch..8ch+7
      const float4* s4 = (const float4*)(p.W + row * 128 + ch * 8);
      float4 a = s4[0], bq = s4[1];
      w[0]=a.x; w[1]=a.y; w[2]=a.z; w[3]=a.w; w[4]=bq.x; w[5]=bq.y; w[6]=bq.z; w[7]=bq.w;
    } else {                           // chi-permuted: chunk ch = (2s'+hi)
      int sp = ch >> 1, hi = ch & 1;
      int kb = 32 * (sp >> 1) + 16 * (sp & 1) + 4 * hi;
      const float* src = p.W + row * 128;
      w[0]=src[kb+0]; w[1]=src[kb+1]; w[2]=src[kb+2];  w[3]=src[kb+3];
      w[4]=src[kb+8]; w[5]=src[kb+9]; w[6]=src[kb+10]; w[7]=src[kb+11];
    }
    wdst[cid * 2 + 0] = make_uint2(pk2(w[0]*s, w[1]*s), pk2(w[2]*s, w[3]*s));
    wdst[cid * 2 + 1] = make_uint2(pk2(w[4]*s, w[5]*s), pk2(w[6]*s, w[7]*s));
  }
  if (t < 128) {
    float s = p.g[t] * rsqrtf(p.v[t] + EPSF);
    biasf[L * 128 + t] = p.b[t] * s + p.be[t] - p.m[t] * s;
  }
}

// Barrier-free persistent encoder, CHANNEL-HALVED layers: each layer's 128 output
// channels are computed in two 64-ch halves -> accs footprint 32 AGPR (was 64),
// which legalizes 16 waves/block = 4 waves/SIMD (reg budget 128: ~85 VGPR + 32
// AGPR fits; the 64-AGPR variant spilled at 4/SIMD twice). Same MFMA count, same
// ds_reads, same epilogue ops — only the schedule changes. chi-order makes the
// split clean: half 0 -> frag[0..3], half 1 -> frag[4..7].
// x loads chunked (xa/xb, 32 regs; r14-validated) into r12-validated 4-phase
// 2KB/wave transpose. L0/L1: D = W'.h. L2: operand-swapped -> lane = OUT
// CHANNEL; per-half in-register segment reduce + atomics.
// LDS: [0,98304) swizzled weights; [98304,131072) 16x2KB transpose regions.
__global__ __launch_bounds__(NTHR) __attribute__((amdgpu_waves_per_eu(4, 4)))
void enc_kernel(const float* __restrict__ x, const int* __restrict__ batch,
                const unsigned short* __restrict__ wsW, const float* __restrict__ biasf,
                float* __restrict__ seg_sum, int* __restrict__ seg_max,
                u32* __restrict__ seg_cnt, int N, int ntiles) {
  __shared__ __attribute__((aligned(16))) unsigned char lds[98304 + NWAVE * 2048];
  __shared__ __attribute__((aligned(16))) float bias_lds[384];
  const int t = threadIdx.x;
  const int lane = t & 63, wv = t >> 6;
  const int l31 = lane & 31, hi = lane >> 5;
  const int swz = l31 & 15;
  const int xaddr = (lane ^ 32) << 2;  // ds_bpermute addr (segment phase only)

  // one-time: stage weights global->LDS with chunk^row swizzle
  {
    const uint4* src = (const uint4*)wsW;
#pragma unroll
    for (int i = 0; i < 6; ++i) {
      int idx = t + i * NTHR;          // 6144 x 16B
      int byte = idx << 4;
      int dst = byte ^ (((byte >> 8) & 15) << 4);  // chunk ^= row&15
      *(uint4*)&lds[dst] = src[idx];
    }
  }
  if (t < 384) bias_lds[t] = biasf[t];
  __syncthreads();                      // the only block barrier

  float bias2[4];
#pragma unroll
  for (int cg = 0; cg < 4; ++cg) bias2[cg] = bias_lds[256 + cg * 32 + l31];

  const int hbase = 98304 + wv * 2048;
  const float4* x4 = (const float4*)x;

  // contiguous balanced tile range for this wave
  const int w = blockIdx.x * NWAVE + wv;         // 0..4095
  const int TW = NBLK * NWAVE;                   // 4096
  const int base = ntiles / TW, rem = ntiles % TW;
  const int t0 = w * base + (w < rem ? w : rem);
  const int t1 = t0 + base + (w < rem ? 1 : 0);

  for (int tile = t0; tile < t1; ++tile) {
    const bool full = (tile * 32 + 32 <= N);
    const float4* xt = x4 + (size_t)tile * 1024 + lane;
    int rr = tile * 32 + l31;
    const int scur = (rr < N) ? batch[rr] : -1;

    // ---- chunked coalesced load + 4-phase transpose (2KB/wave region) ----
    FragU fragA[8], fragB[8];
    {
      float4 xa[4], xb[4];
#pragma unroll
      for (int i = 0; i < 4; ++i)
        xa[i] = full ? xt[i * 64] : make_float4(0.f, 0.f, 0.f, 0.f);
#pragma unroll
      for (int p = 0; p < 4; ++p) {
        const bool odd = (p & 1);
        if (p < 3) {
#pragma unroll
          for (int i = 0; i < 4; ++i) {
            float4 v = full ? xt[((p + 1) * 4 + i) * 64] : make_float4(0.f, 0.f, 0.f, 0.f);
            if (odd) xa[i] = v; else xb[i] = v;
          }
        }
#pragma unroll
        for (int i = 0; i < 4; ++i) {
          int lr = 2 * i + hi;           // local row 0..7 (global row 8p+lr)
          float4 v = odd ? xb[i] : xa[i];
          *(uint2*)&lds[hbase + lr * 256 + ((((l31 >> 1) ^ lr) << 4)) + (l31 & 1) * 8] =
              make_uint2(cvtpk(v.x, v.y), cvtpk(v.z, v.w));
        }
        if ((l31 >> 3) == p) {           // my row lives in this phase
          const int rowp = l31 & 7;
#pragma unroll
          for (int s = 0; s < 8; ++s)
            fragA[s].v = *(const s16x8*)&lds[hbase + rowp * 256 + (((2 * s + hi) ^ rowp) << 4)];
        }
      }
    }

    // ---- dense layer (L0/L1), channel-halved: accs[2] per half ----
    auto dense_layer = [&](int L, FragU (&fin)[8], FragU (&fout)[8]) {
      const int wb = L * 32768 + l31 * 256;
#pragma unroll
      for (int half = 0; half < 2; ++half) {
        f32x16 accs[2];
        {
          f32x16 z = {0,0,0,0,0,0,0,0,0,0,0,0,0,0,0,0};
          accs[0] = z; accs[1] = z;
        }
        __builtin_amdgcn_s_setprio(1);
#pragma unroll
        for (int s = 0; s < 8; ++s)
#pragma unroll
          for (int c2 = 0; c2 < 2; ++c2) {
            const int cg = half * 2 + c2;
            const s16x8 a =
                *(const s16x8*)&lds[wb + cg * 8192 + (((2 * s + hi) ^ swz) << 4)];
            accs[c2] = __builtin_amdgcn_mfma_f32_32x32x16_bf16(a, fin[s].v, accs[c2], 0, 0, 0);
          }
        __builtin_amdgcn_s_setprio(0);
        // bias + relu, pack straight into next-layer frags (chi k-order):
        // cg in {2*half, 2*half+1} -> fout[2cg+kh], kh=0,1
#pragma unroll
        for (int c2 = 0; c2 < 2; ++c2) {
          const int cg = half * 2 + c2;
          float tr[16];
#pragma unroll
          for (int q = 0; q < 4; ++q) {
            int ch = cg * 32 + 4 * hi + 8 * q;   // C/D: c = (r&3) + 8*(r>>2) + 4*hi
            const float4 bb = *(const float4*)&bias_lds[L * 128 + ch];
            tr[4 * q + 0] = fmaxf(accs[c2][4 * q + 0] + bb.x, 0.f);
            tr[4 * q + 1] = fmaxf(accs[c2][4 * q + 1] + bb.y, 0.f);
            tr[4 * q + 2] = fmaxf(accs[c2][4 * q + 2] + bb.z, 0.f);
            tr[4 * q + 3] = fmaxf(accs[c2][4 * q + 3] + bb.w, 0.f);
          }
#pragma unroll
          for (int kh = 0; kh < 2; ++kh) {
            fout[2 * cg + kh].u[0] = cvtpk(tr[8 * kh + 0], tr[8 * kh + 1]);
            fout[2 * cg + kh].u[1] = cvtpk(tr[8 * kh + 2], tr[8 * kh + 3]);
            fout[2 * cg + kh].u[2] = cvtpk(tr[8 * kh + 4], tr[8 * kh + 5]);
            fout[2 * cg + kh].u[3] = cvtpk(tr[8 * kh + 6], tr[8 * kh + 7]);
          }
        }
      }
    };
    dense_layer(0, fragA, fragB);
    dense_layer(1, fragB, fragA);

    // ---- L2 (operand-swapped) + per-half in-register segment reduce ----
    {
      const int wb = 2 * 32768 + l31 * 256;
      const int nvalid = min(N - tile * 32, 32);
      const int sid0 = __builtin_amdgcn_readlane(scur, 0);
      const int sidL = __builtin_amdgcn_readlane(scur, nvalid - 1);
      const bool fast = (nvalid == 32 && sid0 == sidL);
      int srow[16];
      if (!fast) {
#pragma unroll
        for (int rg = 0; rg < 16; ++rg) {
          int m = (rg & 3) + 8 * (rg >> 2) + 4 * hi;
          srow[rg] = __builtin_amdgcn_ds_bpermute(m << 2, scur);
        }
      }
#pragma unroll
      for (int half = 0; half < 2; ++half) {
        f32x16 accs[2];
        {
          f32x16 z = {0,0,0,0,0,0,0,0,0,0,0,0,0,0,0,0};
          accs[0] = z; accs[1] = z;
        }
        __builtin_amdgcn_s_setprio(1);
#pragma unroll
        for (int s = 0; s < 8; ++s)
#pragma unroll
          for (int c2 = 0; c2 < 2; ++c2) {
            const int cg = half * 2 + c2;
            const s16x8 a =
                *(const s16x8*)&lds[wb + cg * 8192 + (((2 * s + hi) ^ swz) << 4)];
            accs[c2] = __builtin_amdgcn_mfma_f32_32x32x16_bf16(fragA[s].v, a, accs[c2], 0, 0, 0);
          }
        __builtin_amdgcn_s_setprio(0);
#pragma unroll
        for (int c2 = 0; c2 < 2; ++c2)
#pragma unroll
          for (int rg = 0; rg < 16; ++rg)
            accs[c2][rg] = fmaxf(accs[c2][rg] + bias2[half * 2 + c2], 0.f);

        if (fast) {
#pragma unroll
          for (int c2 = 0; c2 < 2; ++c2) {
            const int cg = half * 2 + c2;
            float s = 0.f, mx = 0.f;
#pragma unroll
            for (int rg = 0; rg < 16; ++rg) { s += accs[c2][rg]; mx = fmaxf(mx, accs[c2][rg]); }
            float ps = __int_as_float(__builtin_amdgcn_ds_bpermute(xaddr, __float_as_int(s)));
            float pm = __int_as_float(__builtin_amdgcn_ds_bpermute(xaddr, __float_as_int(mx)));
            s += ps; mx = fmaxf(mx, pm);
            if (!hi) {
              atomicAdd(&seg_sum[sid0 * 128 + cg * 32 + l31], s);
              atomicMax(&seg_max[sid0 * 128 + cg * 32 + l31], __float_as_int(mx));
            }
          }
          if (half == 0 && lane == 0) atomicAdd(&seg_cnt[sid0], 32u);
        } else {
          for (int sg = sid0; sg <= sidL; ++sg) {
#pragma unroll
            for (int c2 = 0; c2 < 2; ++c2) {
              const int cg = half * 2 + c2;
              float s = 0.f, mx = 0.f;
#pragma unroll
              for (int rg = 0; rg < 16; ++rg) {
                float v = (srow[rg] == sg) ? accs[c2][rg] : 0.f;
                s += v; mx = fmaxf(mx, v);
              }
              float ps = __int_as_float(__builtin_amdgcn_ds_bpermute(xaddr, __float_as_int(s)));
              float pm = __int_as_float(__builtin_amdgcn_ds_bpermute(xaddr, __float_as_int(mx)));
              s += ps; mx = fmaxf(mx, pm);
              if (!hi) {
                atomicAdd(&seg_sum[sg * 128 + cg * 32 + l31], s);
                atomicMax(&seg_max[sg * 128 + cg * 32 + l31], __float_as_int(mx));
              }
            }
            if (half == 0) {
              u32 c = (u32)__popcll(__ballot(hi == 0 && scur == sg));
              if (lane == 0) atomicAdd(&seg_cnt[sg], c);
            }
          }
        }
      }
    }
  }
}

// out[s,o] = BN( [sum|max|mean] @ Wo^T + bo )
__global__ __launch_bounds__(128)
void proj_kernel(const float* __restrict__ seg_sum, const unsigned* __restrict__ seg_max,
                 const u32* __restrict__ seg_cnt,
                 const float* __restrict__ Wo, const float* __restrict__ bo,
                 const float* __restrict__ go, const float* __restrict__ beo,
                 const float* __restrict__ mo, const float* __restrict__ vo,
                 float* __restrict__ out) {
  __shared__ __attribute__((aligned(16))) float agg[384];
  __shared__ float part[64];
  const int s = blockIdx.x, t = threadIdx.x;
  float cinv = 1.f / fmaxf((float)seg_cnt[s], 1.f);
  for (int i = t; i < 384; i += 128) {
    float v;
    if (i < 128)      v = seg_sum[s * 128 + i];
    else if (i < 256) v = __uint_as_float(seg_max[s * 128 + i - 128]);
    else              v = seg_sum[s * 128 + i - 256] * cinv;
    agg[i] = v;
  }
  __syncthreads();
  const int o = t & 63, hf = t >> 6;
  const float4* wrow = (const float4*)(Wo + o * 384 + hf * 192);
  float acc = 0.f;
#pragma unroll 8
  for (int k4 = 0; k4 < 48; ++k4) {
    float4 w = wrow[k4];
    float4 a = *(const float4*)&agg[hf * 192 + k4 * 4];
    acc += w.x * a.x + w.y * a.y + w.z * a.z + w.w * a.w;
  }
  if (hf) part[o] = acc;
  __syncthreads();
  if (!hf) {
    acc += part[o];
    float sc = go[o] * rsqrtf(vo[o] + EPSF);
    out[s * 64 + o] = (acc + bo[o] - mo[o]) * sc + beo[o];
  }
}

extern "C" void kernel_launch(void* const* d_in, const int* in_sizes, int n_in,
                              void* d_out, int out_size, void* d_ws, size_t ws_size,
                              hipStream_t stream) {
  (void)n_in; (void)out_size; (void)ws_size;
  const float* x = (const float*)d_in[0];
  const int* batch = (const int*)d_in[1];
  LayerP P0{(const float*)d_in[2],  (const float*)d_in[3],  (const float*)d_in[4],
            (const float*)d_in[5],  (const float*)d_in[6],  (const float*)d_in[7]};
  LayerP P1{(const float*)d_in[8],  (const float*)d_in[9],  (const float*)d_in[10],
            (const float*)d_in[11], (const float*)d_in[12], (const float*)d_in[13]};
  LayerP P2{(const float*)d_in[14], (const float*)d_in[15], (const float*)d_in[16],
            (const float*)d_in[17], (const float*)d_in[18], (const float*)d_in[19]};
  const float* Wo  = (const float*)d_in[20];
  const float* bo  = (const float*)d_in[21];
  const float* go  = (const float*)d_in[22];
  const float* beo = (const float*)d_in[23];
  const float* mo  = (const float*)d_in[24];
  const float* vo  = (const float*)d_in[25];
  const int N = in_sizes[0] / 128;

  char* ws = (char*)d_ws;
  float* seg_sum = (float*)ws;                         // 1 MiB
  int*   seg_max = (int*)(ws + (1u << 20));            // 1 MiB (float bits, >=0)
  u32*   seg_cnt = (u32*)(ws + (2u << 20));            // 8 KiB
  unsigned short* wsW = (unsigned short*)(ws + (2u << 20) + 8192);  // 96 KiB
  float* biasf = (float*)(ws + (2u << 20) + 8192 + 98304);          // 1.5 KiB

  const int n16 = ((2 << 20) + 8192) / 16;             // 131584 uint4 to zero
  const int nzero_blk = (n16 + 255) / 256;             // 514
  setup_kernel<<<3 + nzero_blk, 256, 0, stream>>>(P0, P1, P2, wsW, biasf,
                                                  (uint4*)d_ws, n16);
  const int ntiles = (N + 31) / 32;
  enc_kernel<<<NBLK, NTHR, 0, stream>>>(x, batch, wsW, biasf, seg_sum, seg_max, seg_cnt,
                                        N, ntiles);
  proj_kernel<<<NSEG, 128, 0, stream>>>(seg_sum, (const unsigned*)seg_max, seg_cnt,
                                        Wo, bo, go, beo, mo, vo, (float*)d_out);
}

// Round 21
// 102.815 us; speedup vs baseline: 1.6563x; 1.6563x over previous
//
#include <hip/hip_runtime.h>

#define EPSF 1e-5f
#define NSEG 2048
#define NTHR 768     // 12 waves
#define NWAVE 12
#define NBLK 256

typedef short s16x8 __attribute__((ext_vector_type(8)));
typedef float f32x16 __attribute__((ext_vector_type(16)));
typedef unsigned u32;

__device__ __forceinline__ u32 f2bfu(float f) {
  u32 u = __float_as_uint(f);
  u += 0x7FFFu + ((u >> 16) & 1u);  // RNE; no NaN/Inf in data
  return u >> 16;
}
__device__ __forceinline__ u32 pk2(float a, float b) {  // prep path only
  return f2bfu(a) | (f2bfu(b) << 16);
}
// v_cvt_pk_bf16_f32: dst = {lo=bf16(a), hi=bf16(b)} — 1 VALU op
__device__ __forceinline__ u32 cvtpk(float a, float b) {
  u32 r;
  asm("v_cvt_pk_bf16_f32 %0, %1, %2" : "=v"(r) : "v"(a), "v"(b));
  return r;
}

union FragU { s16x8 v; u32 u[4]; };

struct LayerP { const float *W, *b, *g, *be, *m, *v; };

// Fused setup: blocks 0..2 fold BN into weights (bf16; layers 1,2 K-PERMUTED by
// chi(s,hi,j) = 32*(s>>1)+16*(s&1)+4*hi+(j<4 ? j : j+4), the k-order a lane holds
// after the previous layer's MFMA) and compute biases; blocks 3..516 zero the
// 2.1MB seg accumulator region (disjoint writes; one launch instead of two).
__global__ void setup_kernel(LayerP p0, LayerP p1, LayerP p2,
                             unsigned short* __restrict__ wsW,
                             float* __restrict__ biasf,
                             uint4* __restrict__ zp, int n16) {
  const int b = blockIdx.x;
  const int t = threadIdx.x;
  if (b >= 3) {
    int i = (b - 3) * 256 + t;
    if (i < n16) zp[i] = make_uint4(0u, 0u, 0u, 0u);
    return;
  }
  const int L = b;
  LayerP p = (L == 0) ? p0 : ((L == 1) ? p1 : p2);
  uint2* wdst = (uint2*)(wsW + L * 16384);
  for (int i = 0; i < 8; ++i) {
    int cid = t + i * 256;             // 2048 chunks = 128 rows x 16 chunks(16B)
    int row = cid >> 4, ch = cid & 15;
    float s = p.g[row] * rsqrtf(p.v[row] + EPSF);
    float w[8];
    if (L == 0) {                      // natural order: chunk ch = k 8ch..8ch+7
      const float4* s4 = (const float4*)(p.W + row * 128 + ch * 8);
      float4 a = s4[0], bq = s4[1];
      w[0]=a.x; w[1]=a.y; w[2]=a.z; w[3]=a.w; w[4]=bq.x; w[5]=bq.y; w[6]=bq.z; w[7]=bq.w;
    } else {                           // chi-permuted: chunk ch = (2s'+hi)
      int sp = ch >> 1, hi = ch & 1;
      int kb = 32 * (sp >> 1) + 16 * (sp & 1) + 4 * hi;
      const float* src = p.W + row * 128;
      w[0]=src[kb+0]; w[1]=src[kb+1]; w[2]=src[kb+2];  w[3]=src[kb+3];
      w[4]=src[kb+8]; w[5]=src[kb+9]; w[6]=src[kb+10]; w[7]=src[kb+11];
    }
    wdst[cid * 2 + 0] = make_uint2(pk2(w[0]*s, w[1]*s), pk2(w[2]*s, w[3]*s));
    wdst[cid * 2 + 1] = make_uint2(pk2(w[4]*s, w[5]*s), pk2(w[6]*s, w[7]*s));
  }
  if (t < 128) {
    float s = p.g[t] * rsqrtf(p.v[t] + EPSF);
    biasf[L * 128 + t] = p.b[t] * s + p.be[t] - p.m[t] * s;
  }
}

// Barrier-free persistent encoder — round-16/19 kernel (proven best: 103.1us).
// 12 waves/block, 3 waves/SIMD, 84 VGPR + 64 AGPR = 148 <= 170, no spill.
// Register law (5x confirmed: r6,r12,r14,r15/r17,r20): the working set (two
// 32-reg frag buffers + accs + staging) cannot fit the 128-reg envelope of
// 4 waves/SIMD, and no cross-tile prefetch of any size fits 3/SIMD either.
// Direct frag-layout gather (no transpose) caps at ~900 GB/s (r5-r8) — rejected.
// L0/L1: D = W'.h (lane = x-row), k-permuted weights -> no lane exchange.
// L2: operand-swapped mfma(frag, w) -> lane = OUT CHANNEL, rows in regs:
//     segment sum/max reduce in-register, one bpermute, atomics flush.
// LDS: [0,98304) swizzled weights; [98304,147456) 12x4KB transpose regions.
__global__ __launch_bounds__(NTHR) __attribute__((amdgpu_waves_per_eu(3, 3)))
void enc_kernel(const float* __restrict__ x, const int* __restrict__ batch,
                const unsigned short* __restrict__ wsW, const float* __restrict__ biasf,
                float* __restrict__ seg_sum, int* __restrict__ seg_max,
                u32* __restrict__ seg_cnt, int N, int ntiles) {
  __shared__ __attribute__((aligned(16))) unsigned char lds[98304 + NWAVE * 4096];
  __shared__ __attribute__((aligned(16))) float bias_lds[384];
  const int t = threadIdx.x;
  const int lane = t & 63, wv = t >> 6;
  const int l31 = lane & 31, hi = lane >> 5;
  const int swz = l31 & 15;
  const int xaddr = (lane ^ 32) << 2;  // ds_bpermute addr (segment phase only)

  // one-time: stage weights global->LDS with chunk^row swizzle
  {
    const uint4* src = (const uint4*)wsW;
#pragma unroll
    for (int i = 0; i < 8; ++i) {
      int idx = t + i * NTHR;          // 6144 x 16B
      int byte = idx << 4;
      int dst = byte ^ (((byte >> 8) & 15) << 4);  // chunk ^= row&15
      *(uint4*)&lds[dst] = src[idx];
    }
  }
  if (t < 384) bias_lds[t] = biasf[t];
  __syncthreads();                      // the only block barrier

  // L2 bias per-lane (channel cg*32+l31), hoisted out of the tile loop
  float bias2[4];
#pragma unroll
  for (int cg = 0; cg < 4; ++cg) bias2[cg] = bias_lds[256 + cg * 32 + l31];

  const int hbase = 98304 + wv * 4096;
  const float4* x4 = (const float4*)x;

  // contiguous balanced tile range for this wave
  const int w = blockIdx.x * NWAVE + wv;         // 0..3071
  const int TW = NBLK * NWAVE;                   // 3072
  const int base = ntiles / TW, rem = ntiles % TW;
  const int t0 = w * base + (w < rem ? w : rem);
  const int t1 = t0 + base + (w < rem ? 1 : 0);

  for (int tile = t0; tile < t1; ++tile) {
    // ---- coalesced tile load: instr i = bytes [i*1024,(i+1)*1024), lane*16 within ----
    const bool full = (tile * 32 + 32 <= N);
    float4 xr[16];
    {
      const float4* xt = x4 + (size_t)tile * 1024 + lane;
#pragma unroll
      for (int i = 0; i < 16; ++i)
        xr[i] = full ? xt[i * 64] : make_float4(0.f, 0.f, 0.f, 0.f);
    }
    int rr = tile * 32 + l31;
    const int scur = (rr < N) ? batch[rr] : -1;

    // ---- wave-local transpose: two 16-row halves through the 4KB region ----
    FragU frag[8];
#pragma unroll
    for (int h = 0; h < 2; ++h) {
#pragma unroll
      for (int i = 0; i < 8; ++i) {
        int rowp = 2 * i + hi;           // LDS-local row 0..15 (global row 16h+rowp)
        float4 v = xr[8 * h + i];
        *(uint2*)&lds[hbase + rowp * 256 + ((((l31 >> 1) ^ rowp) << 4)) + (l31 & 1) * 8] =
            make_uint2(cvtpk(v.x, v.y), cvtpk(v.z, v.w));
      }
      if ((l31 >> 4) == h) {             // my row lives in this half
        const int rowp = l31 & 15;
#pragma unroll
        for (int s = 0; s < 8; ++s)
          frag[s].v = *(const s16x8*)&lds[hbase + rowp * 256 + (((2 * s + hi) ^ rowp) << 4)];
      }
    }

    // ---- 3 fused layers (k-permuted weights; no inter-layer exchange) ----
    f32x16 accs[4];
#pragma unroll
    for (int L = 0; L < 3; ++L) {
      const int wb = L * 32768 + l31 * 256;
#pragma unroll
      for (int cg = 0; cg < 4; ++cg) {
        f32x16 z = {0,0,0,0,0,0,0,0,0,0,0,0,0,0,0,0};
        accs[cg] = z;
      }
      __builtin_amdgcn_s_setprio(1);
#pragma unroll
      for (int s = 0; s < 8; ++s) {
#pragma unroll
        for (int cg = 0; cg < 4; ++cg) {
          const s16x8 a =
              *(const s16x8*)&lds[wb + cg * 8192 + (((2 * s + hi) ^ swz) << 4)];
          if (L < 2)
            accs[cg] = __builtin_amdgcn_mfma_f32_32x32x16_bf16(a, frag[s].v, accs[cg], 0, 0, 0);
          else  // swapped: D = h2 . W2'^T, lane = out-channel, rows in regs
            accs[cg] = __builtin_amdgcn_mfma_f32_32x32x16_bf16(frag[s].v, a, accs[cg], 0, 0, 0);
        }
      }
      __builtin_amdgcn_s_setprio(0);
      if (L < 2) {
        // bias + relu, pack straight into next-layer frags (chi k-order)
#pragma unroll
        for (int cg = 0; cg < 4; ++cg) {
          float tr[16];
#pragma unroll
          for (int q = 0; q < 4; ++q) {
            int ch = cg * 32 + 4 * hi + 8 * q;   // C/D: c = (r&3) + 8*(r>>2) + 4*hi
            const float4 bb = *(const float4*)&bias_lds[L * 128 + ch];
            tr[4 * q + 0] = fmaxf(accs[cg][4 * q + 0] + bb.x, 0.f);
            tr[4 * q + 1] = fmaxf(accs[cg][4 * q + 1] + bb.y, 0.f);
            tr[4 * q + 2] = fmaxf(accs[cg][4 * q + 2] + bb.z, 0.f);
            tr[4 * q + 3] = fmaxf(accs[cg][4 * q + 3] + bb.w, 0.f);
          }
#pragma unroll
          for (int kh = 0; kh < 2; ++kh) {
            frag[2 * cg + kh].u[0] = cvtpk(tr[8 * kh + 0], tr[8 * kh + 1]);
            frag[2 * cg + kh].u[1] = cvtpk(tr[8 * kh + 2], tr[8 * kh + 3]);
            frag[2 * cg + kh].u[2] = cvtpk(tr[8 * kh + 4], tr[8 * kh + 5]);
            frag[2 * cg + kh].u[3] = cvtpk(tr[8 * kh + 6], tr[8 * kh + 7]);
          }
        }
      }
    }

    // ---- segment phase, in-register (lane = channel cg*32+l31; 16 rows in regs) ----
    // row of accs[cg][rg] (global within tile) = (rg&3) + 8*(rg>>2) + 4*hi
    const int nvalid = min(N - tile * 32, 32);
    const int sid0 = __builtin_amdgcn_readlane(scur, 0);
    const int sidL = __builtin_amdgcn_readlane(scur, nvalid - 1);
#pragma unroll
    for (int cg = 0; cg < 4; ++cg)
#pragma unroll
      for (int rg = 0; rg < 16; ++rg)
        accs[cg][rg] = fmaxf(accs[cg][rg] + bias2[cg], 0.f);

    if (nvalid == 32 && sid0 == sidL) {
      // fast path: whole tile in one segment
#pragma unroll
      for (int cg = 0; cg < 4; ++cg) {
        float s = 0.f, mx = 0.f;
#pragma unroll
        for (int rg = 0; rg < 16; ++rg) { s += accs[cg][rg]; mx = fmaxf(mx, accs[cg][rg]); }
        float ps = __int_as_float(__builtin_amdgcn_ds_bpermute(xaddr, __float_as_int(s)));
        float pm = __int_as_float(__builtin_amdgcn_ds_bpermute(xaddr, __float_as_int(mx)));
        s += ps; mx = fmaxf(mx, pm);
        if (!hi) {
          atomicAdd(&seg_sum[sid0 * 128 + cg * 32 + l31], s);
          atomicMax(&seg_max[sid0 * 128 + cg * 32 + l31], __float_as_int(mx));
        }
      }
      if (lane == 0) atomicAdd(&seg_cnt[sid0], 32u);
    } else {
      // slow path: per-row sids via bpermute, loop over the (small) sid range
      int srow[16];
#pragma unroll
      for (int rg = 0; rg < 16; ++rg) {
        int m = (rg & 3) + 8 * (rg >> 2) + 4 * hi;
        srow[rg] = __builtin_amdgcn_ds_bpermute(m << 2, scur);
      }
      for (int sg = sid0; sg <= sidL; ++sg) {
#pragma unroll
        for (int cg = 0; cg < 4; ++cg) {
          float s = 0.f, mx = 0.f;
#pragma unroll
          for (int rg = 0; rg < 16; ++rg) {
            float v = (srow[rg] == sg) ? accs[cg][rg] : 0.f;
            s += v; mx = fmaxf(mx, v);
          }
          float ps = __int_as_float(__builtin_amdgcn_ds_bpermute(xaddr, __float_as_int(s)));
          float pm = __int_as_float(__builtin_amdgcn_ds_bpermute(xaddr, __float_as_int(mx)));
          s += ps; mx = fmaxf(mx, pm);
          if (!hi) {
            atomicAdd(&seg_sum[sg * 128 + cg * 32 + l31], s);
            atomicMax(&seg_max[sg * 128 + cg * 32 + l31], __float_as_int(mx));
          }
        }
        u32 c = (u32)__popcll(__ballot(hi == 0 && scur == sg));
        if (lane == 0) atomicAdd(&seg_cnt[sg], c);
      }
    }
  }
}

// out[s,o] = BN( [sum|max|mean] @ Wo^T + bo )
__global__ __launch_bounds__(128)
void proj_kernel(const float* __restrict__ seg_sum, const unsigned* __restrict__ seg_max,
                 const u32* __restrict__ seg_cnt,
                 const float* __restrict__ Wo, const float* __restrict__ bo,
                 const float* __restrict__ go, const float* __restrict__ beo,
                 const float* __restrict__ mo, const float* __restrict__ vo,
                 float* __restrict__ out) {
  __shared__ __attribute__((aligned(16))) float agg[384];
  __shared__ float part[64];
  const int s = blockIdx.x, t = threadIdx.x;
  float cinv = 1.f / fmaxf((float)seg_cnt[s], 1.f);
  for (int i = t; i < 384; i += 128) {
    float v;
    if (i < 128)      v = seg_sum[s * 128 + i];
    else if (i < 256) v = __uint_as_float(seg_max[s * 128 + i - 128]);
    else              v = seg_sum[s * 128 + i - 256] * cinv;
    agg[i] = v;
  }
  __syncthreads();
  const int o = t & 63, hf = t >> 6;
  const float4* wrow = (const float4*)(Wo + o * 384 + hf * 192);
  float acc = 0.f;
#pragma unroll 8
  for (int k4 = 0; k4 < 48; ++k4) {
    float4 w = wrow[k4];
    float4 a = *(const float4*)&agg[hf * 192 + k4 * 4];
    acc += w.x * a.x + w.y * a.y + w.z * a.z + w.w * a.w;
  }
  if (hf) part[o] = acc;
  __syncthreads();
  if (!hf) {
    acc += part[o];
    float sc = go[o] * rsqrtf(vo[o] + EPSF);
    out[s * 64 + o] = (acc + bo[o] - mo[o]) * sc + beo[o];
  }
}

extern "C" void kernel_launch(void* const* d_in, const int* in_sizes, int n_in,
                              void* d_out, int out_size, void* d_ws, size_t ws_size,
                              hipStream_t stream) {
  (void)n_in; (void)out_size; (void)ws_size;
  const float* x = (const float*)d_in[0];
  const int* batch = (const int*)d_in[1];
  LayerP P0{(const float*)d_in[2],  (const float*)d_in[3],  (const float*)d_in[4],
            (const float*)d_in[5],  (const float*)d_in[6],  (const float*)d_in[7]};
  LayerP P1{(const float*)d_in[8],  (const float*)d_in[9],  (const float*)d_in[10],
            (const float*)d_in[11], (const float*)d_in[12], (const float*)d_in[13]};
  LayerP P2{(const float*)d_in[14], (const float*)d_in[15], (const float*)d_in[16],
            (const float*)d_in[17], (const float*)d_in[18], (const float*)d_in[19]};
  const float* Wo  = (const float*)d_in[20];
  const float* bo  = (const float*)d_in[21];
  const float* go  = (const float*)d_in[22];
  const float* beo = (const float*)d_in[23];
  const float* mo  = (const float*)d_in[24];
  const float* vo  = (const float*)d_in[25];
  const int N = in_sizes[0] / 128;

  char* ws = (char*)d_ws;
  float* seg_sum = (float*)ws;                         // 1 MiB
  int*   seg_max = (int*)(ws + (1u << 20));            // 1 MiB (float bits, >=0)
  u32*   seg_cnt = (u32*)(ws + (2u << 20));            // 8 KiB
  unsigned short* wsW = (unsigned short*)(ws + (2u << 20) + 8192);  // 96 KiB
  float* biasf = (float*)(ws + (2u << 20) + 8192 + 98304);          // 1.5 KiB

  const int n16 = ((2 << 20) + 8192) / 16;             // 131584 uint4 to zero
  const int nzero_blk = (n16 + 255) / 256;             // 514
  setup_kernel<<<3 + nzero_blk, 256, 0, stream>>>(P0, P1, P2, wsW, biasf,
                                                  (uint4*)d_ws, n16);
  const int ntiles = (N + 31) / 32;
  enc_kernel<<<NBLK, NTHR, 0, stream>>>(x, batch, wsW, biasf, seg_sum, seg_max, seg_cnt,
                                        N, ntiles);
  proj_kernel<<<NSEG, 128, 0, stream>>>(seg_sum, (const unsigned*)seg_max, seg_cnt,
                                        Wo, bo, go, beo, mo, vo, (float*)d_out);
}